// Round 6
// baseline (179.210 us; speedup 1.0000x reference)
//
#include <hip/hip_runtime.h>

constexpr int EMB  = 128;   // EMB_DIM
constexpr int H1D  = 256;   // 2*HIDDEN
constexpr int H2D  = 128;   // HIDDEN
constexpr int VOC  = 4096;  // VOCAB
constexpr int NSL  = 32;    // wsum slices (atomic-contention spreading)
constexpr int RPB  = 4;     // emb rows per tile in embW1 GEMM

// LDS-privatized histogram: 8 node-ranges x 64 edge-slice teams = 512 blocks.
// Counts packed 2 x u16 per u32 word (per-team slice count <= 12.5K < 65536, so
// no carry between halves): LDS 12.8 KB -> 12 blocks/CU co-resident, u32-wide
// writeout. Partials stored as u16 (6.4 MB total).
constexpr int NRANGE = 8;
constexpr int TEAMS  = 64;
constexpr int RCAPW  = 3200;                  // packed words capacity (12.8 KB)
constexpr int HIST_B = NRANGE * TEAMS;        // 512 (first in grid: critical path)
constexpr int GEMM_B = VOC / RPB;             // 1024
constexpr int KB_GRID = HIST_B + GEMM_B;      // 1536

// ---------------- kA: zero state; block 0 builds flagbits + count from x_position.
// cnt[] is NOT zeroed: k_alloc fully writes it before any reader.
__global__ void kA_init(int* count, unsigned int* flagbits, unsigned int* needw,
                        float* wagg, float* wsum, int* nflag, int* total,
                        const int* __restrict__ xpos,
                        int n, int nwords, int np) {
    int t = threadIdx.x;
    if (blockIdx.x == 0) {
        for (int i = t; i < nwords; i += 256) flagbits[i] = 0u;
        for (int i = t; i < n; i += 256) count[i] = 0;
        __syncthreads();
        for (int i = t; i < np; i += 256) {
            int v = xpos[i];
            atomicAdd(&count[v], 1);
            atomicOr(&flagbits[v >> 5], 1u << (v & 31));
        }
        if (t == 0) { *nflag = 0; *total = 0; }
    } else {
        const int stride = (gridDim.x - 1) * 256;
        const int i0 = (blockIdx.x - 1) * 256 + t;
        for (int i = i0; i < n; i += stride) wagg[i] = 0.0f;
        for (int i = i0; i < nwords; i += stride) needw[i] = 0u;
        for (int i = i0; i < NSL * H1D; i += stride) wsum[i] = 0.0f;
    }
}

// ---------------- kB: blocks [0,512): LDS-privatized histogram + needed-row marks
//                  || blocks [512,1536): embW1 = emb @ W1 (one 4-row tile each).
// Hist block h: team = h/8 (owns a 12.5K-edge slice), range = h&7 (owns nodes
// [range*R, range*R+R), R even). Counts in packed-u16 LDS (no global atomics),
// written out as plain coalesced u32 stores. Flag-test + mark runs once per edge
// (in the unique owning range block).
__global__ __launch_bounds__(256) void kB_embW1_hist(
        const float* __restrict__ emb, const float* __restrict__ W1,
        float* __restrict__ embW1,
        const int* __restrict__ row, const int* __restrict__ col,
        const unsigned int* __restrict__ flagbits,
        unsigned short* __restrict__ cntp16, unsigned int* markw,
        int ne, int R, int sTeam) {
    __shared__ unsigned int sbuf[RCAPW];     // 12.8 KB (GEMM path reuses 2 KB)
    int t = threadIdx.x;
    if (blockIdx.x < HIST_B) {
        int h     = blockIdx.x;
        int team  = h >> 3;                  // / NRANGE
        int range = h & (NRANGE - 1);
        int base  = range * R;
        int RW    = R >> 1;                  // packed words (R even)
        for (int i = t; i < RW; i += 256) sbuf[i] = 0u;
        __syncthreads();
        int q  = (((ne + TEAMS - 1) / TEAMS) + 255) & ~255;   // 256-aligned slice
        int e0 = team * q;
        int e1 = min(ne, e0 + q);
        for (int e = e0 + t; e < e1; e += 256) {
            int c = col[e];
            unsigned int d = (unsigned int)(c - base);
            if (d < (unsigned int)R) {
                atomicAdd(&sbuf[d >> 1], 1u << ((d & 1) << 4));   // LDS atomic
                if ((flagbits[c >> 5] >> (c & 31)) & 1u) {        // ~2% of edges
                    int r = row[e];
                    atomicOr(&markw[r >> 5], 1u << (r & 31));
                }
            }
        }
        __syncthreads();
        unsigned int* outp32 =
            (unsigned int*)(cntp16 + (size_t)team * sTeam + base);  // 4B-aligned
        for (int i = t; i < RW; i += 256) outp32[i] = sbuf[i];
    } else {
        float (*er)[EMB] = (float (*)[EMB])sbuf;   // 2 KB of sbuf
        int r0 = (blockIdx.x - HIST_B) * RPB;
        for (int i = t; i < RPB * EMB; i += 256)
            er[i / EMB][i % EMB] = emb[(size_t)r0 * EMB + i];
        __syncthreads();
        float acc[RPB];
#pragma unroll
        for (int rr = 0; rr < RPB; rr++) acc[rr] = 0.0f;
        for (int k = 0; k < EMB; k++) {
            float w = W1[k * H1D + t];
#pragma unroll
            for (int rr = 0; rr < RPB; rr++) acc[rr] += er[rr][k] * w;
        }
#pragma unroll
        for (int rr = 0; rr < RPB; rr++)
            embW1[(size_t)(r0 + rr) * H1D + t] = acc[rr];
    }
}

// ------- k_alloc: cv = sum of 64 u16 histogram partials (written to cnt[]);
//         need = mark||flag; canonical needbits via wave-ballot plain store;
//         CSR bump-alloc (wave-aggregated atomics); wagg self term;
//         packed pkc[v] = {cnt:16, x:16} (4B) so scatter/fconv move half the bytes.
//         (cv fits u16: avg in-degree 16, random graph; max deg << 65536.)
__global__ void k_alloc(unsigned int* needw,
                        const unsigned int* __restrict__ flagbits,
                        const unsigned short* __restrict__ cntp16,
                        const int* __restrict__ count,
                        const int* __restrict__ x,
                        float* wagg, int* needlist, int* nflag, int* total,
                        int* offs, int* cursor, unsigned int* pkc, int* cnt,
                        int n, int sTeam) {
    int v = blockIdx.x * blockDim.x + threadIdx.x;
    int lane = threadIdx.x & 63;
    int cv = 0;
    bool need = false;
    if (v < n) {
        const unsigned short* cp = cntp16 + v;
#pragma unroll 8
        for (int tt = 0; tt < TEAMS; tt++) cv += cp[(size_t)tt * sTeam];
        cnt[v] = cv;
        pkc[v] = ((unsigned int)cv << 16) | (unsigned int)(x[v] & 0xFFFF);
        bool mark = (needw[v >> 5] >> (v & 31)) & 1u;
        bool flag = (flagbits[v >> 5] >> (v & 31)) & 1u;
        need = mark || flag;
        if (flag) wagg[v] = (float)count[v] / ((float)cv + 1.0f);  // count*dinv^2
    }
    // canonical needbits: ballot -> one word per half-wave, plain store by owner lane
    unsigned long long nm = __ballot(need);
    int wbase = (v & ~63) >> 5;            // v is wave-aligned at lane 0
    if (lane == 0)  needw[wbase]     = (unsigned int)(nm & 0xffffffffu);
    if (lane == 32) needw[wbase + 1] = (unsigned int)(nm >> 32);
    int seg = need ? cv : 0;
    int incl = seg;
#pragma unroll
    for (int d = 1; d < 64; d <<= 1) {
        int t2 = __shfl_up(incl, d);
        if (lane >= d) incl += t2;
    }
    int excl = incl - seg;
    int wave_total = __shfl(incl, 63);
    int rank = __popcll(nm & ((1ull << lane) - 1));
    int wcnt = __popcll(nm);
    int base_id = 0, base_off = 0;
    if (lane == 0) {
        if (wcnt > 0)       base_id  = atomicAdd(nflag, wcnt);
        if (wave_total > 0) base_off = atomicAdd(total, wave_total);
    }
    base_id  = __shfl(base_id, 0);
    base_off = __shfl(base_off, 0);
    if (need) {
        needlist[base_id + rank] = v;
        int o = base_off + excl;
        offs[v] = o;
        cursor[v] = o;
    }
}

// ---------------- k_scatter: filtered to needed cols via L1-resident bitmask;
//   srow4[pos] = pkc[row] (single 4B gather + 4B store); wagg edge terms
//   (flagged only, ~2%) recompute dinv from packed cnt (bit-identical rsqrtf).
__global__ void k_scatter(const int* __restrict__ row, const int* __restrict__ col,
                          const unsigned int* __restrict__ needw,
                          const unsigned int* __restrict__ flagbits,
                          const int* __restrict__ count,
                          const unsigned int* __restrict__ pkc,
                          int* cursor, unsigned int* srow4, float* wagg, int ne) {
    int e = blockIdx.x * blockDim.x + threadIdx.x;
    if (e < ne) {
        int c = col[e];
        if ((needw[c >> 5] >> (c & 31)) & 1u) {
            int r = row[e];
            int pos = atomicAdd(&cursor[c], 1);
            unsigned int pr = pkc[r];
            srow4[pos] = pr;
            if ((flagbits[c >> 5] >> (c & 31)) & 1u) {    // ~2% of edges
                float dr = rsqrtf((float)(pr >> 16) + 1.0f);
                float dc = rsqrtf((float)(pkc[c] >> 16) + 1.0f);
                atomicAdd(&wagg[r], (float)count[c] * dc * dr);
            }
        }
    }
}

// -------------------- fused conv1+conv2 over needed nodes (proven body):
//   wsum += wagg[v] * relu( b1 + dv^2*embW1[x[v]] + sum_e d_r*dv*embW1[x_r] )
__global__ void k_fconv(const int* __restrict__ needlist, const int* __restrict__ nneed_p,
                        const float* __restrict__ wagg, const int* __restrict__ x,
                        const unsigned int* __restrict__ srow4,
                        const int* __restrict__ offs, const int* __restrict__ cnt,
                        const float* __restrict__ embW1, const float* __restrict__ b1,
                        float* __restrict__ wsum) {
    int lane = threadIdx.x & 63;
    int wib  = threadIdx.x >> 6;
    int wid  = blockIdx.x * (blockDim.x >> 6) + wib;
    int nw   = gridDim.x * (blockDim.x >> 6);
    int nn   = *nneed_p;
    const float4* __restrict__ ew = (const float4*)embW1;   // row r = ew + r*64
    float4 bfrag = ((const float4*)b1)[lane];
    float4 acc2 = {0.0f, 0.0f, 0.0f, 0.0f};

    for (int i = wid; i < nn; i += nw) {
        int v = needlist[i];
        int cv = cnt[v];
        float dv = rsqrtf((float)cv + 1.0f);
        float wa = wagg[v];
        float4 s = ew[(size_t)x[v] * 64 + lane];
        float w0 = dv * dv;
        float4 acc;
        acc.x = bfrag.x + w0 * s.x;
        acc.y = bfrag.y + w0 * s.y;
        acc.z = bfrag.z + w0 * s.z;
        acc.w = bfrag.w + w0 * s.w;
        int start = offs[v], m = cv;
        for (int base = 0; base < m; base += 64) {
            int mm = min(64, m - base);
            int xr = 0; float wr = 0.0f;
            if (lane < mm) {
                unsigned int pk2 = srow4[start + base + lane];   // one 4B load
                xr = (int)(pk2 & 0xFFFFu);
                wr = rsqrtf((float)(pk2 >> 16) + 1.0f) * dv;     // == dr * dv
            }
            int e = 0;
            for (; e + 4 <= mm; e += 4) {
                int i0 = __shfl(xr, e),     i1 = __shfl(xr, e + 1);
                int i2 = __shfl(xr, e + 2), i3 = __shfl(xr, e + 3);
                float q0 = __shfl(wr, e),     q1 = __shfl(wr, e + 1);
                float q2 = __shfl(wr, e + 2), q3 = __shfl(wr, e + 3);
                float4 t0 = ew[(size_t)i0 * 64 + lane];
                float4 t1 = ew[(size_t)i1 * 64 + lane];
                float4 t2 = ew[(size_t)i2 * 64 + lane];
                float4 t3 = ew[(size_t)i3 * 64 + lane];
                acc.x += q0 * t0.x + q1 * t1.x + q2 * t2.x + q3 * t3.x;
                acc.y += q0 * t0.y + q1 * t1.y + q2 * t2.y + q3 * t3.y;
                acc.z += q0 * t0.z + q1 * t1.z + q2 * t2.z + q3 * t3.z;
                acc.w += q0 * t0.w + q1 * t1.w + q2 * t2.w + q3 * t3.w;
            }
            for (; e < mm; e++) {
                int i0 = __shfl(xr, e);
                float q0 = __shfl(wr, e);
                float4 t0 = ew[(size_t)i0 * 64 + lane];
                acc.x += q0 * t0.x;
                acc.y += q0 * t0.y;
                acc.z += q0 * t0.z;
                acc.w += q0 * t0.w;
            }
        }
        acc2.x += wa * fmaxf(acc.x, 0.0f);
        acc2.y += wa * fmaxf(acc.y, 0.0f);
        acc2.z += wa * fmaxf(acc.z, 0.0f);
        acc2.w += wa * fmaxf(acc.w, 0.0f);
    }

    __shared__ float red[4][H1D];
    red[wib][4 * lane + 0] = acc2.x;
    red[wib][4 * lane + 1] = acc2.y;
    red[wib][4 * lane + 2] = acc2.z;
    red[wib][4 * lane + 3] = acc2.w;
    __syncthreads();
    int t = threadIdx.x;
    float ssum = red[0][t] + red[1][t] + red[2][t] + red[3][t];
    atomicAdd(&wsum[(blockIdx.x & (NSL - 1)) * H1D + t], ssum);
}

// ---------- k_zout: 256 blocks x 16 cols (full-chip). Each block: reduce wsum
// slices, compute z = b2 + (ws@W2)/NP (redundant per block, tiny), then 16 output
// cols with a 16-way j-split + LDS reduce.
__global__ void k_zout(const float* __restrict__ wsum, const float* __restrict__ W2,
                       const float* __restrict__ b2, const float* __restrict__ Wc,
                       const float* __restrict__ bc, float* __restrict__ out,
                       float inv_np) {
    __shared__ float ws[H1D];
    __shared__ float z[H2D];
    __shared__ float red[256];
    int t = threadIdx.x;
    float s = 0.0f;
#pragma unroll
    for (int c2 = 0; c2 < NSL; c2++) s += wsum[c2 * H1D + t];
    ws[t] = s;
    __syncthreads();
    if (t < H2D) {
        float acc = 0.0f;
#pragma unroll 8
        for (int k = 0; k < H1D; k++) acc += ws[k] * W2[k * H2D + t];
        z[t] = b2[t] + acc * inv_np;
    }
    __syncthreads();
    int c  = blockIdx.x * 16 + (t & 15);
    int js = t >> 4;                       // 0..15, each covers 8 j's
    float acc = 0.0f;
#pragma unroll
    for (int j = js * 8; j < js * 8 + 8; j++) acc += z[j] * Wc[(size_t)j * VOC + c];
    red[t] = acc;
    __syncthreads();
    if (t < 16) {
        int cc = blockIdx.x * 16 + t;
        float o = bc[cc];
#pragma unroll
        for (int ss = 0; ss < 16; ss++) o += red[ss * 16 + t];
        out[cc] = o;
    }
}

extern "C" void kernel_launch(void* const* d_in, const int* in_sizes, int n_in,
                              void* d_out, int out_size, void* d_ws, size_t ws_size,
                              hipStream_t stream) {
    const int n  = in_sizes[0];
    const int ne = in_sizes[1] / 2;
    const int np = in_sizes[2];

    const int*   x    = (const int*)d_in[0];
    const int*   ei   = (const int*)d_in[1];
    const int*   xpos = (const int*)d_in[2];
    const float* emb  = (const float*)d_in[3];
    const float* W1   = (const float*)d_in[4];
    const float* b1   = (const float*)d_in[5];
    const float* W2   = (const float*)d_in[6];
    const float* b2   = (const float*)d_in[7];
    const float* Wc   = (const float*)d_in[8];
    const float* bc   = (const float*)d_in[9];
    float*       out  = (float*)d_out;

    const int* row = ei;       // edge_index[0]
    const int* col = ei + ne;  // edge_index[1]

    char* p = (char*)d_ws;
    auto alloc = [&](size_t bytes) {
        char* r = p;
        p += (bytes + 255) & ~(size_t)255;
        return r;
    };
    const int nb     = (n + 255) / 256;
    const int neb    = (ne + 255) / 256;
    const int nwords = nb * 8;   // (nb*256)/32 — padded so ballot stores stay in-bounds
    // nodes per histogram range: even (packed-u16 words), <= 2*RCAPW
    const int R      = (((n + NRANGE - 1) / NRANGE) + 1) & ~1;
    const int sTeam  = NRANGE * R;                  // per-team partial stride (>= n, even)

    int*            cnt      = (int*)alloc((size_t)n * 4);
    int*            offs     = (int*)alloc((size_t)n * 4);
    int*            cursor   = (int*)alloc((size_t)n * 4);
    int*            count    = (int*)alloc((size_t)n * 4);
    int*            needlist = (int*)alloc((size_t)n * 4);
    unsigned int*   needw    = (unsigned int*)alloc((size_t)nwords * 4);
    unsigned int*   flagbits = (unsigned int*)alloc((size_t)nwords * 4);
    unsigned int*   srow4    = (unsigned int*)alloc((size_t)ne * 4);
    unsigned int*   pkc      = (unsigned int*)alloc((size_t)n * 4);
    unsigned short* cntp16   = (unsigned short*)alloc((size_t)TEAMS * sTeam * 2);
    int*            nflag    = (int*)alloc(256 * 4);
    int*            total    = (int*)alloc(256 * 4);
    float*          wagg     = (float*)alloc((size_t)n * 4);
    float*          embW1    = (float*)alloc((size_t)VOC * H1D * 4);
    float*          wsum     = (float*)alloc((size_t)NSL * H1D * 4);

    kA_init<<<nb, 256, 0, stream>>>(count, flagbits, needw, wagg, wsum,
                                    nflag, total, xpos, n, nwords, np);
    kB_embW1_hist<<<KB_GRID, 256, 0, stream>>>(emb, W1, embW1, row, col, flagbits,
                                               cntp16, needw, ne, R, sTeam);
    k_alloc<<<nb, 256, 0, stream>>>(needw, flagbits, cntp16, count, x, wagg,
                                    needlist, nflag, total, offs, cursor, pkc, cnt,
                                    n, sTeam);
    k_scatter<<<neb, 256, 0, stream>>>(row, col, needw, flagbits, count, pkc,
                                       cursor, srow4, wagg, ne);
    k_fconv<<<2048, 256, 0, stream>>>(needlist, nflag, wagg, x, srow4, offs, cnt,
                                      embW1, b1, wsum);
    k_zout<<<VOC / 16, 256, 0, stream>>>(wsum, W2, b2, Wc, bc, out, 1.0f / (float)np);
}

// Round 8
// 171.461 us; speedup vs baseline: 1.0452x; 1.0452x over previous
//
#include <hip/hip_runtime.h>

constexpr int EMB  = 128;   // EMB_DIM
constexpr int H1D  = 256;   // 2*HIDDEN
constexpr int H2D  = 128;   // HIDDEN
constexpr int VOC  = 4096;  // VOCAB
constexpr int NSL  = 32;    // wsum slices (atomic-contention spreading)
constexpr int RPB  = 4;     // emb rows per tile in embW1 GEMM
constexpr int KT   = 16;    // W1 k-tile staged in LDS per GEMM iteration

// LDS-privatized histogram (R5-proven geometry): 8 node-ranges x 128 edge-slice
// teams = 1024 blocks, 24-iter sweeps, u32 LDS counts (25.6 KB), u16 partials.
constexpr int NRANGE = 8;
constexpr int TEAMS  = 128;
constexpr int RCAP   = 6400;                  // u32 words (25.6 KB)
constexpr int HIST_B = NRANGE * TEAMS;        // 1024 (first in grid)
constexpr int GEMM_B = VOC / RPB;             // 1024
constexpr int KB_GRID = HIST_B + GEMM_B;      // 2048

// ---------------- kA: zero state; block 0 builds flagbits + count from x_position.
// cnt[] is NOT zeroed: k_alloc fully writes it before any reader.
__global__ void kA_init(int* count, unsigned int* flagbits, unsigned int* needw,
                        float* wagg, float* wsum, int* nflag, int* total,
                        const int* __restrict__ xpos,
                        int n, int nwords, int np) {
    int t = threadIdx.x;
    if (blockIdx.x == 0) {
        for (int i = t; i < nwords; i += 256) flagbits[i] = 0u;
        for (int i = t; i < n; i += 256) count[i] = 0;
        __syncthreads();
        for (int i = t; i < np; i += 256) {
            int v = xpos[i];
            atomicAdd(&count[v], 1);
            atomicOr(&flagbits[v >> 5], 1u << (v & 31));
        }
        if (t == 0) { *nflag = 0; *total = 0; }
    } else {
        const int stride = (gridDim.x - 1) * 256;
        const int i0 = (blockIdx.x - 1) * 256 + t;
        for (int i = i0; i < n; i += stride) wagg[i] = 0.0f;
        for (int i = i0; i < nwords; i += stride) needw[i] = 0u;
        for (int i = i0; i < NSL * H1D; i += stride) wsum[i] = 0.0f;
    }
}

// ---------------- kB: blocks [0,1024): LDS-privatized histogram + needed-row marks
//                  || blocks [1024,2048): embW1 = emb @ W1 (one 4-row tile each).
// GEMM side is restructured for MLP: W1 staged in LDS k-tiles of 16 via 4
// independent float4 loads/thread (one exposed latency per tile, 8 tiles total)
// instead of 128 dependent scalar L2 loads. Inner loop: conflict-free LDS reads
// (lane-consecutive) + broadcast er reads + FMA, fully unrolled.
__global__ __launch_bounds__(256) void kB_embW1_hist(
        const float* __restrict__ emb, const float* __restrict__ W1,
        float* __restrict__ embW1,
        const int* __restrict__ row, const int* __restrict__ col,
        const unsigned int* __restrict__ flagbits,
        unsigned short* __restrict__ cntp16, unsigned int* markw,
        int ne, int R, int sTeam) {
    __shared__ unsigned int sbuf[RCAP];      // 25.6 KB (GEMM uses 18 KB of it)
    int t = threadIdx.x;
    if (blockIdx.x < HIST_B) {
        int h     = blockIdx.x;
        int team  = h >> 3;                  // / NRANGE
        int range = h & (NRANGE - 1);
        int base  = range * R;
        for (int i = t; i < R; i += 256) sbuf[i] = 0u;
        __syncthreads();
        int q  = (((ne + TEAMS - 1) / TEAMS) + 255) & ~255;   // 256-aligned slice
        int e0 = team * q;
        int e1 = min(ne, e0 + q);
        for (int e = e0 + t; e < e1; e += 256) {
            int c = col[e];
            unsigned int d = (unsigned int)(c - base);
            if (d < (unsigned int)R) {
                atomicAdd(&sbuf[d], 1u);                       // LDS atomic
                if ((flagbits[c >> 5] >> (c & 31)) & 1u) {     // ~2% of edges
                    int r = row[e];
                    atomicOr(&markw[r >> 5], 1u << (r & 31));
                }
            }
        }
        __syncthreads();
        unsigned short* outp = cntp16 + (size_t)team * sTeam + base;
        for (int i = t; i < R; i += 256) outp[i] = (unsigned short)sbuf[i];
    } else {
        float* sf = (float*)sbuf;
        float (*er)[EMB]  = (float (*)[EMB])sf;               // 2 KB
        float (*w1t)[H1D] = (float (*)[H1D])(sf + RPB * EMB); // 16 KB
        int r0 = (blockIdx.x - HIST_B) * RPB;
        // emb tile: 512 floats = 128 float4, threads 0..127 (visible after the
        // first staging barrier below)
        if (t < RPB * EMB / 4)
            ((float4*)er)[t] = ((const float4*)(emb + (size_t)r0 * EMB))[t];
        float acc[RPB];
#pragma unroll
        for (int rr = 0; rr < RPB; rr++) acc[rr] = 0.0f;
#pragma unroll
        for (int kt = 0; kt < EMB / KT; kt++) {   // 8 k-tiles
            __syncthreads();   // previous tile's readers done (no-op at kt=0)
            const float4* w4 = (const float4*)(W1 + (size_t)kt * KT * H1D);
#pragma unroll
            for (int i = 0; i < KT * H1D / 4 / 256; i++)      // 4 independent f4
                ((float4*)w1t)[t + i * 256] = w4[t + i * 256];
            __syncthreads();   // w1t (and er at kt=0) visible
#pragma unroll
            for (int k2 = 0; k2 < KT; k2++) {
                float w = w1t[k2][t];
                int k = kt * KT + k2;
#pragma unroll
                for (int rr = 0; rr < RPB; rr++) acc[rr] += er[rr][k] * w;
            }
        }
#pragma unroll
        for (int rr = 0; rr < RPB; rr++)
            embW1[(size_t)(r0 + rr) * H1D + t] = acc[rr];
    }
}

// ------- k_alloc: cv = sum of 128 u16 histogram partials (written to cnt[]);
//         need = mark||flag; canonical needbits via wave-ballot plain store;
//         CSR bump-alloc (wave-aggregated atomics); wagg self term;
//         packed pkc[v] = {cnt:16, x:16} (4B) so scatter/fconv move half the bytes.
__global__ void k_alloc(unsigned int* needw,
                        const unsigned int* __restrict__ flagbits,
                        const unsigned short* __restrict__ cntp16,
                        const int* __restrict__ count,
                        const int* __restrict__ x,
                        float* wagg, int* needlist, int* nflag, int* total,
                        int* offs, int* cursor, unsigned int* pkc, int* cnt,
                        int n, int sTeam) {
    int v = blockIdx.x * blockDim.x + threadIdx.x;
    int lane = threadIdx.x & 63;
    int cv = 0;
    bool need = false;
    if (v < n) {
        const unsigned short* cp = cntp16 + v;
#pragma unroll 8
        for (int tt = 0; tt < TEAMS; tt++) cv += cp[(size_t)tt * sTeam];
        cnt[v] = cv;
        pkc[v] = ((unsigned int)cv << 16) | (unsigned int)(x[v] & 0xFFFF);
        bool mark = (needw[v >> 5] >> (v & 31)) & 1u;
        bool flag = (flagbits[v >> 5] >> (v & 31)) & 1u;
        need = mark || flag;
        if (flag) wagg[v] = (float)count[v] / ((float)cv + 1.0f);  // count*dinv^2
    }
    // canonical needbits: ballot -> one word per half-wave, plain store by owner lane
    unsigned long long nm = __ballot(need);
    int wbase = (v & ~63) >> 5;            // v is wave-aligned at lane 0
    if (lane == 0)  needw[wbase]     = (unsigned int)(nm & 0xffffffffu);
    if (lane == 32) needw[wbase + 1] = (unsigned int)(nm >> 32);
    int seg = need ? cv : 0;
    int incl = seg;
#pragma unroll
    for (int d = 1; d < 64; d <<= 1) {
        int t2 = __shfl_up(incl, d);
        if (lane >= d) incl += t2;
    }
    int excl = incl - seg;
    int wave_total = __shfl(incl, 63);
    int rank = __popcll(nm & ((1ull << lane) - 1));
    int wcnt = __popcll(nm);
    int base_id = 0, base_off = 0;
    if (lane == 0) {
        if (wcnt > 0)       base_id  = atomicAdd(nflag, wcnt);
        if (wave_total > 0) base_off = atomicAdd(total, wave_total);
    }
    base_id  = __shfl(base_id, 0);
    base_off = __shfl(base_off, 0);
    if (need) {
        needlist[base_id + rank] = v;
        int o = base_off + excl;
        offs[v] = o;
        cursor[v] = o;
    }
}

// ---------------- k_scatter: filtered to needed cols via L1-resident bitmask;
//   srow4[pos] = pkc[row] (single 4B gather + 4B store); wagg edge terms
//   (flagged only, ~2%) recompute dinv from packed cnt (bit-identical rsqrtf).
__global__ void k_scatter(const int* __restrict__ row, const int* __restrict__ col,
                          const unsigned int* __restrict__ needw,
                          const unsigned int* __restrict__ flagbits,
                          const int* __restrict__ count,
                          const unsigned int* __restrict__ pkc,
                          int* cursor, unsigned int* srow4, float* wagg, int ne) {
    int e = blockIdx.x * blockDim.x + threadIdx.x;
    if (e < ne) {
        int c = col[e];
        if ((needw[c >> 5] >> (c & 31)) & 1u) {
            int r = row[e];
            int pos = atomicAdd(&cursor[c], 1);
            unsigned int pr = pkc[r];
            srow4[pos] = pr;
            if ((flagbits[c >> 5] >> (c & 31)) & 1u) {    // ~2% of edges
                float dr = rsqrtf((float)(pr >> 16) + 1.0f);
                float dc = rsqrtf((float)(pkc[c] >> 16) + 1.0f);
                atomicAdd(&wagg[r], (float)count[c] * dc * dr);
            }
        }
    }
}

// -------------------- fused conv1+conv2 over needed nodes (proven body):
//   wsum += wagg[v] * relu( b1 + dv^2*embW1[x[v]] + sum_e d_r*dv*embW1[x_r] )
__global__ void k_fconv(const int* __restrict__ needlist, const int* __restrict__ nneed_p,
                        const float* __restrict__ wagg, const int* __restrict__ x,
                        const unsigned int* __restrict__ srow4,
                        const int* __restrict__ offs, const int* __restrict__ cnt,
                        const float* __restrict__ embW1, const float* __restrict__ b1,
                        float* __restrict__ wsum) {
    int lane = threadIdx.x & 63;
    int wib  = threadIdx.x >> 6;
    int wid  = blockIdx.x * (blockDim.x >> 6) + wib;
    int nw   = gridDim.x * (blockDim.x >> 6);
    int nn   = *nneed_p;
    const float4* __restrict__ ew = (const float4*)embW1;   // row r = ew + r*64
    float4 bfrag = ((const float4*)b1)[lane];
    float4 acc2 = {0.0f, 0.0f, 0.0f, 0.0f};

    for (int i = wid; i < nn; i += nw) {
        int v = needlist[i];
        int cv = cnt[v];
        float dv = rsqrtf((float)cv + 1.0f);
        float wa = wagg[v];
        float4 s = ew[(size_t)x[v] * 64 + lane];
        float w0 = dv * dv;
        float4 acc;
        acc.x = bfrag.x + w0 * s.x;
        acc.y = bfrag.y + w0 * s.y;
        acc.z = bfrag.z + w0 * s.z;
        acc.w = bfrag.w + w0 * s.w;
        int start = offs[v], m = cv;
        for (int base = 0; base < m; base += 64) {
            int mm = min(64, m - base);
            int xr = 0; float wr = 0.0f;
            if (lane < mm) {
                unsigned int pk2 = srow4[start + base + lane];   // one 4B load
                xr = (int)(pk2 & 0xFFFFu);
                wr = rsqrtf((float)(pk2 >> 16) + 1.0f) * dv;     // == dr * dv
            }
            int e = 0;
            for (; e + 4 <= mm; e += 4) {
                int i0 = __shfl(xr, e),     i1 = __shfl(xr, e + 1);
                int i2 = __shfl(xr, e + 2), i3 = __shfl(xr, e + 3);
                float q0 = __shfl(wr, e),     q1 = __shfl(wr, e + 1);
                float q2 = __shfl(wr, e + 2), q3 = __shfl(wr, e + 3);
                float4 t0 = ew[(size_t)i0 * 64 + lane];
                float4 t1 = ew[(size_t)i1 * 64 + lane];
                float4 t2 = ew[(size_t)i2 * 64 + lane];
                float4 t3 = ew[(size_t)i3 * 64 + lane];
                acc.x += q0 * t0.x + q1 * t1.x + q2 * t2.x + q3 * t3.x;
                acc.y += q0 * t0.y + q1 * t1.y + q2 * t2.y + q3 * t3.y;
                acc.z += q0 * t0.z + q1 * t1.z + q2 * t2.z + q3 * t3.z;
                acc.w += q0 * t0.w + q1 * t1.w + q2 * t2.w + q3 * t3.w;
            }
            for (; e < mm; e++) {
                int i0 = __shfl(xr, e);
                float q0 = __shfl(wr, e);
                float4 t0 = ew[(size_t)i0 * 64 + lane];
                acc.x += q0 * t0.x;
                acc.y += q0 * t0.y;
                acc.z += q0 * t0.z;
                acc.w += q0 * t0.w;
            }
        }
        acc2.x += wa * fmaxf(acc.x, 0.0f);
        acc2.y += wa * fmaxf(acc.y, 0.0f);
        acc2.z += wa * fmaxf(acc.z, 0.0f);
        acc2.w += wa * fmaxf(acc.w, 0.0f);
    }

    __shared__ float red[4][H1D];
    red[wib][4 * lane + 0] = acc2.x;
    red[wib][4 * lane + 1] = acc2.y;
    red[wib][4 * lane + 2] = acc2.z;
    red[wib][4 * lane + 3] = acc2.w;
    __syncthreads();
    int t = threadIdx.x;
    float ssum = red[0][t] + red[1][t] + red[2][t] + red[3][t];
    atomicAdd(&wsum[(blockIdx.x & (NSL - 1)) * H1D + t], ssum);
}

// ---------- k_zout: 256 blocks x 16 cols (full-chip). Each block: reduce wsum
// slices, compute z = b2 + (ws@W2)/NP (redundant per block, tiny), then 16 output
// cols with a 16-way j-split + LDS reduce.
__global__ void k_zout(const float* __restrict__ wsum, const float* __restrict__ W2,
                       const float* __restrict__ b2, const float* __restrict__ Wc,
                       const float* __restrict__ bc, float* __restrict__ out,
                       float inv_np) {
    __shared__ float ws[H1D];
    __shared__ float z[H2D];
    __shared__ float red[256];
    int t = threadIdx.x;
    float s = 0.0f;
#pragma unroll
    for (int c2 = 0; c2 < NSL; c2++) s += wsum[c2 * H1D + t];
    ws[t] = s;
    __syncthreads();
    if (t < H2D) {
        float acc = 0.0f;
#pragma unroll 8
        for (int k = 0; k < H1D; k++) acc += ws[k] * W2[k * H2D + t];
        z[t] = b2[t] + acc * inv_np;
    }
    __syncthreads();
    int c  = blockIdx.x * 16 + (t & 15);
    int js = t >> 4;                       // 0..15, each covers 8 j's
    float acc = 0.0f;
#pragma unroll
    for (int j = js * 8; j < js * 8 + 8; j++) acc += z[j] * Wc[(size_t)j * VOC + c];
    red[t] = acc;
    __syncthreads();
    if (t < 16) {
        int cc = blockIdx.x * 16 + t;
        float o = bc[cc];
#pragma unroll
        for (int ss = 0; ss < 16; ss++) o += red[ss * 16 + t];
        out[cc] = o;
    }
}

extern "C" void kernel_launch(void* const* d_in, const int* in_sizes, int n_in,
                              void* d_out, int out_size, void* d_ws, size_t ws_size,
                              hipStream_t stream) {
    const int n  = in_sizes[0];
    const int ne = in_sizes[1] / 2;
    const int np = in_sizes[2];

    const int*   x    = (const int*)d_in[0];
    const int*   ei   = (const int*)d_in[1];
    const int*   xpos = (const int*)d_in[2];
    const float* emb  = (const float*)d_in[3];
    const float* W1   = (const float*)d_in[4];
    const float* b1   = (const float*)d_in[5];
    const float* W2   = (const float*)d_in[6];
    const float* b2   = (const float*)d_in[7];
    const float* Wc   = (const float*)d_in[8];
    const float* bc   = (const float*)d_in[9];
    float*       out  = (float*)d_out;

    const int* row = ei;       // edge_index[0]
    const int* col = ei + ne;  // edge_index[1]

    char* p = (char*)d_ws;
    auto alloc = [&](size_t bytes) {
        char* r = p;
        p += (bytes + 255) & ~(size_t)255;
        return r;
    };
    const int nb     = (n + 255) / 256;
    const int neb    = (ne + 255) / 256;
    const int nwords = nb * 8;   // (nb*256)/32 — padded so ballot stores stay in-bounds
    const int R      = (n + NRANGE - 1) / NRANGE;   // nodes per histogram range (<=RCAP)
    const int sTeam  = NRANGE * R;                  // per-team partial stride (>= n)

    int*            cnt      = (int*)alloc((size_t)n * 4);
    int*            offs     = (int*)alloc((size_t)n * 4);
    int*            cursor   = (int*)alloc((size_t)n * 4);
    int*            count    = (int*)alloc((size_t)n * 4);
    int*            needlist = (int*)alloc((size_t)n * 4);
    unsigned int*   needw    = (unsigned int*)alloc((size_t)nwords * 4);
    unsigned int*   flagbits = (unsigned int*)alloc((size_t)nwords * 4);
    unsigned int*   srow4    = (unsigned int*)alloc((size_t)ne * 4);
    unsigned int*   pkc      = (unsigned int*)alloc((size_t)n * 4);
    unsigned short* cntp16   = (unsigned short*)alloc((size_t)TEAMS * sTeam * 2);
    int*            nflag    = (int*)alloc(256 * 4);
    int*            total    = (int*)alloc(256 * 4);
    float*          wagg     = (float*)alloc((size_t)n * 4);
    float*          embW1    = (float*)alloc((size_t)VOC * H1D * 4);
    float*          wsum     = (float*)alloc((size_t)NSL * H1D * 4);

    kA_init<<<nb, 256, 0, stream>>>(count, flagbits, needw, wagg, wsum,
                                    nflag, total, xpos, n, nwords, np);
    kB_embW1_hist<<<KB_GRID, 256, 0, stream>>>(emb, W1, embW1, row, col, flagbits,
                                               cntp16, needw, ne, R, sTeam);
    k_alloc<<<nb, 256, 0, stream>>>(needw, flagbits, cntp16, count, x, wagg,
                                    needlist, nflag, total, offs, cursor, pkc, cnt,
                                    n, sTeam);
    k_scatter<<<neb, 256, 0, stream>>>(row, col, needw, flagbits, count, pkc,
                                       cursor, srow4, wagg, ne);
    k_fconv<<<2048, 256, 0, stream>>>(needlist, nflag, wagg, x, srow4, offs, cnt,
                                      embW1, b1, wsum);
    k_zout<<<VOC / 16, 256, 0, stream>>>(wsum, W2, b2, Wc, bc, out, 1.0f / (float)np);
}